// Round 2
// baseline (9761.853 us; speedup 1.0000x reference)
//
#include <hip/hip_runtime.h>
#include <hip/hip_bf16.h>
#include <math.h>

typedef __hip_bfloat16 bf16;

#define IMG 128
#define CIN 96
#define CH  192
#define SCALE_Q 0.2041241452319315f   // 24^-0.5

__device__ __forceinline__ float toF(bf16 x) { return __bfloat162float(x); }
__device__ __forceinline__ bf16 toB(float x) { return __float2bfloat16(x); }

// ---------- block-wide LayerNorm stats over 192 threads (3 waves) ----------
__device__ __forceinline__ void stats192(float v, float* red, int tid,
                                         float& mean, float& rstd) {
  float s = v, s2 = v * v;
  #pragma unroll
  for (int off = 32; off > 0; off >>= 1) {
    s  += __shfl_xor(s, off, 64);
    s2 += __shfl_xor(s2, off, 64);
  }
  const int wave = tid >> 6;
  if ((tid & 63) == 0) { red[wave] = s; red[3 + wave] = s2; }
  __syncthreads();
  const float S  = red[0] + red[1] + red[2];
  const float S2 = red[3] + red[4] + red[5];
  mean = S * (1.0f / 192.0f);
  const float var = S2 * (1.0f / 192.0f) - mean * mean;
  rstd = rsqrtf(var + 1e-5f);
  __syncthreads();   // red reusable afterwards
}

// ---------- kernel 1: 3x3 conv (pad 1), NCHW in -> token-major (tok, C) bf16 ----------
// block: 128 threads = one image row; each thread computes 16 output channels.
__global__ __launch_bounds__(128) void conv3x3_tok(
    const float* __restrict__ in, const float* __restrict__ wgt,
    const float* __restrict__ bias, bf16* __restrict__ out_tok) {
  const int x = threadIdx.x;
  int bz = blockIdx.x;
  const int cog = bz % 12; bz /= 12;      // 12 groups of 16 channels
  const int y = bz & 127;
  const int b = bz >> 7;
  const int co0 = cog * 16;
  float acc[16];
  #pragma unroll
  for (int g = 0; g < 16; ++g) acc[g] = bias[co0 + g];
  const float* inb = in + (b * CIN) * IMG * IMG;
  for (int ci = 0; ci < CIN; ++ci) {
    const float* plane = inb + ci * IMG * IMG;
    const float* wp = wgt + co0 * CIN * 9 + ci * 9;
    #pragma unroll
    for (int ky = 0; ky < 3; ++ky) {
      const int yy = y + ky - 1;
      if (yy < 0 || yy >= IMG) continue;
      const float* row = plane + yy * IMG;
      #pragma unroll
      for (int kx = 0; kx < 3; ++kx) {
        const int xx = x + kx - 1;
        const float iv = (xx >= 0 && xx < IMG) ? row[xx] : 0.0f;
        const float* wk = wp + ky * 3 + kx;
        #pragma unroll
        for (int g = 0; g < 16; ++g)
          acc[g] = fmaf(iv, wk[g * CIN * 9], acc[g]);
      }
    }
  }
  const int tok = (b * IMG + y) * IMG + x;
  bf16 tmp[16];
  #pragma unroll
  for (int g = 0; g < 16; ++g) tmp[g] = toB(acc[g]);
  uint4* o = (uint4*)(out_tok + (size_t)tok * CH + co0);
  o[0] = *(const uint4*)(tmp);
  o[1] = *(const uint4*)(tmp + 8);
}

// ---------- kernel 2: LN1/LN2 + q/k/v projection + res=xp+vp (in-place), 8 tokens/block ----------
__global__ __launch_bounds__(192) void ln_qkv(
    bf16* __restrict__ xp, const bf16* __restrict__ vp,
    const float* __restrict__ n1w, const float* __restrict__ n1b,
    const float* __restrict__ n2w, const float* __restrict__ n2b,
    const float* __restrict__ qW, const float* __restrict__ kvW,
    bf16* __restrict__ qb, bf16* __restrict__ kb, bf16* __restrict__ vb) {
  const int tid = threadIdx.x;
  const int tok0 = blockIdx.x * 8;
  __shared__ __align__(16) float xs[8 * 192];
  __shared__ __align__(16) float vs[8 * 192];
  __shared__ float red[6];
  const size_t base = (size_t)tok0 * 192;
  for (int i = tid; i < 1536; i += 192) {
    const float xv = toF(xp[base + i]);
    const float vv = toF(vp[base + i]);
    xs[i] = xv;
    vs[i] = vv;
    xp[base + i] = toB(xv + vv);     // residual sum, in-place (xp dead as raw after this kernel)
  }
  __syncthreads();
  const float w1 = n1w[tid], b1 = n1b[tid];
  const float w2 = n2w[tid], b2 = n2b[tid];
  for (int tk = 0; tk < 8; ++tk) {
    float mean, rstd;
    const float vx = xs[tk * 192 + tid];
    stats192(vx, red, tid, mean, rstd);
    xs[tk * 192 + tid] = (vx - mean) * rstd * w1 + b1;
    const float vv = vs[tk * 192 + tid];
    stats192(vv, red, tid, mean, rstd);
    vs[tk * 192 + tid] = (vv - mean) * rstd * w2 + b2;
  }
  __syncthreads();

  float qa[8], ka[8], va[8];
  #pragma unroll
  for (int tk = 0; tk < 8; ++tk) { qa[tk] = 0.f; ka[tk] = 0.f; va[tk] = 0.f; }
  const float4* qr = (const float4*)(qW + tid * 192);
  const float4* kr = (const float4*)(kvW + tid * 192);
  const float4* vr = (const float4*)(kvW + (192 + tid) * 192);
  const float4* xs4 = (const float4*)xs;
  const float4* vs4 = (const float4*)vs;
  for (int i = 0; i < 48; ++i) {
    const float4 qw = qr[i], kw = kr[i], vw = vr[i];
    #pragma unroll
    for (int tk = 0; tk < 8; ++tk) {
      const float4 xv = xs4[tk * 48 + i];
      const float4 vv = vs4[tk * 48 + i];
      qa[tk] += xv.x*qw.x + xv.y*qw.y + xv.z*qw.z + xv.w*qw.w;
      ka[tk] += vv.x*kw.x + vv.y*kw.y + vv.z*kw.z + vv.w*kw.w;
      va[tk] += vv.x*vw.x + vv.y*vw.y + vv.z*vw.z + vv.w*vw.w;
    }
  }
  // token -> (window, in-window-token); 8 consecutive tokens share a window row
  const int b   = tok0 >> 14;
  const int rem = tok0 & 16383;
  const int y   = rem >> 7;
  const int x0  = rem & 127;                 // multiple of 8
  const int wi  = b * 256 + ((y >> 3) << 4) + (x0 >> 3);
  const int t0  = (y & 7) * 8;
  const int h = tid / 24, d = tid - h * 24;
  const size_t off = ((size_t)(wi * 8 + h) * 64 + t0) * 24 + d;
  bf16* qd = qb + off;
  bf16* kd = kb + off;
  bf16* vd = vb + off;
  #pragma unroll
  for (int tk = 0; tk < 8; ++tk) {
    qd[tk * 24] = toB(qa[tk] * SCALE_Q);
    kd[tk * 24] = toB(ka[tk]);
    vd[tk * 24] = toB(va[tk]);
  }
}

// ---------- kernel 3: windowed attention, one block per (window, head) ----------
__global__ __launch_bounds__(64) void attn64(
    const bf16* __restrict__ qb, const bf16* __restrict__ kb,
    const bf16* __restrict__ vb, const float* __restrict__ rpb,
    bf16* __restrict__ fb) {
  const int wh = blockIdx.x;           // w*8 + h
  const int h = wh & 7;
  const int w = wh >> 3;
  const int t = threadIdx.x;
  __shared__ __align__(16) float ks[64 * 24];
  __shared__ __align__(16) float vs[64 * 24];
  __shared__ float bsh[225];
  const bf16* kbase = kb + (size_t)wh * 1536;
  const bf16* vbase = vb + (size_t)wh * 1536;
  for (int i = t; i < 1536; i += 64) { ks[i] = toF(kbase[i]); vs[i] = toF(vbase[i]); }
  for (int i = t; i < 225; i += 64) bsh[i] = rpb[i * 8 + h];
  float q[24];
  const bf16* qrow = qb + ((size_t)wh * 64 + t) * 24;
  #pragma unroll
  for (int d = 0; d < 24; ++d) q[d] = toF(qrow[d]);
  __syncthreads();
  const int qy = t >> 3, qx = t & 7;
  float s[64];
  float mx = -1e30f;
  #pragma unroll
  for (int kk = 0; kk < 64; ++kk) {
    float acc = 0.f;
    #pragma unroll
    for (int d = 0; d < 24; ++d) acc += q[d] * ks[kk * 24 + d];
    const int ky = kk >> 3, kx = kk & 7;
    acc += bsh[(qy - ky + 7) * 15 + (qx - kx + 7)];
    s[kk] = acc;
    mx = fmaxf(mx, acc);
  }
  float sum = 0.f;
  #pragma unroll
  for (int kk = 0; kk < 64; ++kk) { const float e = __expf(s[kk] - mx); s[kk] = e; sum += e; }
  const float inv = 1.0f / sum;
  float o[24];
  #pragma unroll
  for (int d = 0; d < 24; ++d) o[d] = 0.f;
  #pragma unroll
  for (int kk = 0; kk < 64; ++kk) {
    const float p = s[kk];
    #pragma unroll
    for (int d = 0; d < 24; ++d) o[d] += p * vs[kk * 24 + d];
  }
  bf16* orow = fb + ((size_t)w * 64 + t) * 192 + h * 24;
  #pragma unroll
  for (int d = 0; d < 24; ++d) orow[d] = toB(o[d] * inv);
}

// ---------- kernel 4: attn-proj + LN3, in-place on fb (window-major), 8 tokens/block ----------
__global__ __launch_bounds__(192) void ap_ln3(
    bf16* __restrict__ fb, const float* __restrict__ apW,
    const float* __restrict__ apb,
    const float* __restrict__ n3w, const float* __restrict__ n3b) {
  const int tid = threadIdx.x;
  const int wt0 = blockIdx.x * 8;      // window-major token index
  __shared__ __align__(16) float si[8 * 192];
  __shared__ float red[6];
  const size_t base = (size_t)wt0 * 192;
  for (int i = tid; i < 1536; i += 192) si[i] = toF(fb[base + i]);
  __syncthreads();
  float a[8];
  #pragma unroll
  for (int tk = 0; tk < 8; ++tk) a[tk] = 0.f;
  const float4* wr = (const float4*)(apW + tid * 192);
  const float4* s4 = (const float4*)si;
  for (int i = 0; i < 48; ++i) {
    const float4 wv = wr[i];
    #pragma unroll
    for (int tk = 0; tk < 8; ++tk) {
      const float4 xv = s4[tk * 48 + i];
      a[tk] += xv.x*wv.x + xv.y*wv.y + xv.z*wv.z + xv.w*wv.w;
    }
  }
  const float bb = apb[tid];
  const float w3 = n3w[tid], b3 = n3b[tid];
  #pragma unroll
  for (int tk = 0; tk < 8; ++tk) {
    const float val = a[tk] + bb;
    float mean, rstd;
    stats192(val, red, tid, mean, rstd);
    fb[base + tk * 192 + tid] = toB((val - mean) * rstd * w3 + b3);
  }
}

// ---------- kernel 5: fc1 + exact GELU + fc2 + x2 + LN4 + residual + NCHW store ----------
__global__ __launch_bounds__(192) void mlp_out(
    const bf16* __restrict__ m, const float* __restrict__ w1,
    const float* __restrict__ b1, const float* __restrict__ w2,
    const float* __restrict__ b2,
    const float* __restrict__ n4w, const float* __restrict__ n4b,
    const bf16* __restrict__ res, float* __restrict__ out) {
  const int tid = threadIdx.x;
  const int tok0 = blockIdx.x * 8;     // token-major
  const int b = tok0 >> 14; const int rem = tok0 & 16383;
  const int y = rem >> 7; const int x0 = rem & 127;
  const int wi = b * 256 + ((y >> 3) << 4) + (x0 >> 3);
  const int wt0 = wi * 64 + (y & 7) * 8;
  __shared__ __align__(16) float ms[8 * 192];
  __shared__ __align__(16) float hs[8 * 768];
  __shared__ float red[6];
  const size_t mbase = (size_t)wt0 * 192;
  for (int i = tid; i < 1536; i += 192) ms[i] = toF(m[mbase + i]);
  __syncthreads();
  const float4* ms4 = (const float4*)ms;
  #pragma unroll
  for (int j = 0; j < 4; ++j) {
    const int hrow = tid + 192 * j;
    float acc[8];
    #pragma unroll
    for (int tk = 0; tk < 8; ++tk) acc[tk] = 0.f;
    const float4* wr = (const float4*)(w1 + (size_t)hrow * 192);
    for (int i = 0; i < 48; ++i) {
      const float4 wv = wr[i];
      #pragma unroll
      for (int tk = 0; tk < 8; ++tk) {
        const float4 xv = ms4[tk * 48 + i];
        acc[tk] += xv.x*wv.x + xv.y*wv.y + xv.z*wv.z + xv.w*wv.w;
      }
    }
    const float bb = b1[hrow];
    #pragma unroll
    for (int tk = 0; tk < 8; ++tk) {
      float xg = acc[tk] + bb;
      xg = 0.5f * xg * (1.0f + erff(xg * 0.7071067811865475f));
      hs[tk * 768 + hrow] = xg;
    }
  }
  __syncthreads();
  float a[8];
  #pragma unroll
  for (int tk = 0; tk < 8; ++tk) a[tk] = 0.f;
  const float4* wr2 = (const float4*)(w2 + (size_t)tid * 768);
  const float4* h4 = (const float4*)hs;
  for (int i = 0; i < 192; ++i) {
    const float4 wv = wr2[i];
    #pragma unroll
    for (int tk = 0; tk < 8; ++tk) {
      const float4 xv = h4[tk * 192 + i];
      a[tk] += xv.x*wv.x + xv.y*wv.y + xv.z*wv.z + xv.w*wv.w;
    }
  }
  const float bb = b2[tid];
  const float w4 = n4w[tid], b4 = n4b[tid];
  float rs[8];
  #pragma unroll
  for (int tk = 0; tk < 8; ++tk)
    rs[tk] = toF(res[(size_t)(tok0 + tk) * 192 + tid]);
  float* orow = out + ((size_t)(b * 192 + tid) * 128 + y) * 128 + x0;
  #pragma unroll
  for (int tk = 0; tk < 8; ++tk) {
    const float val = 2.0f * (a[tk] + bb);   // m = m + m
    float mean, rstd;
    stats192(val, red, tid, mean, rstd);
    orow[tk] = (val - mean) * rstd * w4 + b4 + rs[tk];
  }
}

extern "C" void kernel_launch(void* const* d_in, const int* in_sizes, int n_in,
                              void* d_out, int out_size, void* d_ws, size_t ws_size,
                              hipStream_t stream) {
  (void)in_sizes; (void)n_in; (void)out_size; (void)ws_size;
  const float* x    = (const float*)d_in[0];
  const float* v    = (const float*)d_in[1];
  const float* pq_w = (const float*)d_in[2];
  const float* pq_b = (const float*)d_in[3];
  const float* pv_w = (const float*)d_in[4];
  const float* pv_b = (const float*)d_in[5];
  const float* n1w  = (const float*)d_in[6];
  const float* n1b  = (const float*)d_in[7];
  const float* n2w  = (const float*)d_in[8];
  const float* n2b  = (const float*)d_in[9];
  const float* n3w  = (const float*)d_in[10];
  const float* n3b  = (const float*)d_in[11];
  const float* n4w  = (const float*)d_in[12];
  const float* n4b  = (const float*)d_in[13];
  const float* qW   = (const float*)d_in[14];
  const float* kvW  = (const float*)d_in[15];
  const float* apW  = (const float*)d_in[16];
  const float* apb  = (const float*)d_in[17];
  const float* rpb  = (const float*)d_in[18];
  const float* w1   = (const float*)d_in[19];
  const float* b1   = (const float*)d_in[20];
  const float* w2   = (const float*)d_in[21];
  const float* b2   = (const float*)d_in[22];
  float* out = (float*)d_out;

  // Workspace: 3 bf16 half-slots (151 MB). q/k live in d_out (2 half-slots,
  // dead before the final kernel overwrites every element of d_out).
  const size_t HE = 25165824;           // elements per half-slot (tokens*192)
  bf16* xp   = (bf16*)d_ws;             // conv(x) -> res (in-place in ln_qkv)
  bf16* vp   = xp + HE;                 // conv(v) -> fb (attn out) -> m (LN3, in-place)
  bf16* vvb  = vp + HE;                 // v projection
  bf16* qb   = (bf16*)d_out;            // q (scratch in d_out)
  bf16* kb   = qb + HE;                 // k (scratch in d_out)
  bf16* fb   = vp;                      // alias: vp dead after ln_qkv

  conv3x3_tok<<<12288, 128, 0, stream>>>(x, pq_w, pq_b, xp);
  conv3x3_tok<<<12288, 128, 0, stream>>>(v, pv_w, pv_b, vp);
  ln_qkv<<<16384, 192, 0, stream>>>(xp, vp, n1w, n1b, n2w, n2b, qW, kvW, qb, kb, vvb);
  attn64<<<16384, 64, 0, stream>>>(qb, kb, vvb, rpb, fb);
  ap_ln3<<<16384, 192, 0, stream>>>(fb, apW, apb, n3w, n3b);
  mlp_out<<<16384, 192, 0, stream>>>(fb, w1, b1, w2, b2, n4w, n4b, xp, out);
}

// Round 3
// 4963.985 us; speedup vs baseline: 1.9665x; 1.9665x over previous
//
#include <hip/hip_runtime.h>
#include <hip/hip_bf16.h>
#include <math.h>

typedef _Float16 f16;
typedef _Float16 half8 __attribute__((ext_vector_type(8)));
typedef float f32x4 __attribute__((ext_vector_type(4)));

#define IMG 128
#define CIN 96
#define CH  192
#define SCALE_Q 0.2041241452319315f   // 24^-0.5

__device__ __forceinline__ f32x4 mfma16(half8 a, half8 b, f32x4 c) {
  return __builtin_amdgcn_mfma_f32_16x16x32_f16(a, b, c, 0, 0, 0);
}

// load 8 consecutive K-elements of weight row `row` (fp32, row-major [N][K]) -> f16 frag
__device__ __forceinline__ half8 loadBf(const float* __restrict__ W, int row, int k, int ldk) {
  const float* p = W + (size_t)row * ldk + k;
  const float4 a = *(const float4*)p;
  const float4 b = *(const float4*)(p + 4);
  half8 h;
  h[0] = (f16)a.x; h[1] = (f16)a.y; h[2] = (f16)a.z; h[3] = (f16)a.w;
  h[4] = (f16)b.x; h[5] = (f16)b.y; h[6] = (f16)b.z; h[7] = (f16)b.w;
  return h;
}

// exact-GELU via Abramowitz-Stegun erf approx (|err| <= 1.5e-7)
__device__ __forceinline__ float gelu(float x) {
  const float u = 0.70710678118654752f * x;
  const float a = fabsf(u);
  const float t = 1.0f / (1.0f + 0.3275911f * a);
  const float poly = t * (0.254829592f + t * (-0.284496736f +
                     t * (1.421413741f + t * (-1.453152027f + t * 1.061405429f))));
  float er = 1.0f - poly * __expf(-u * u);
  er = (u < 0.f) ? -er : er;
  return 0.5f * x * (1.0f + er);
}

// ---------- kernel 1: 3x3 conv (pad 1), NCHW fp32 in -> token-major (tok, C) f16 ----------
__global__ __launch_bounds__(128) void conv3x3_tok(
    const float* __restrict__ in, const float* __restrict__ wgt,
    const float* __restrict__ bias, f16* __restrict__ out_tok) {
  const int x = threadIdx.x;
  int bz = blockIdx.x;
  const int cog = bz % 12; bz /= 12;      // 12 groups of 16 channels
  const int y = bz & 127;
  const int b = bz >> 7;
  const int co0 = cog * 16;
  float acc[16];
  #pragma unroll
  for (int g = 0; g < 16; ++g) acc[g] = bias[co0 + g];
  const float* inb = in + (size_t)(b * CIN) * IMG * IMG;
  for (int ci = 0; ci < CIN; ++ci) {
    const float* plane = inb + (size_t)ci * IMG * IMG;
    const float* wp = wgt + (size_t)co0 * CIN * 9 + ci * 9;
    #pragma unroll
    for (int ky = 0; ky < 3; ++ky) {
      const int yy = y + ky - 1;
      if (yy < 0 || yy >= IMG) continue;
      const float* row = plane + yy * IMG;
      #pragma unroll
      for (int kx = 0; kx < 3; ++kx) {
        const int xx = x + kx - 1;
        const float iv = (xx >= 0 && xx < IMG) ? row[xx] : 0.0f;
        const float* wk = wp + ky * 3 + kx;
        #pragma unroll
        for (int g = 0; g < 16; ++g)
          acc[g] = fmaf(iv, wk[g * CIN * 9], acc[g]);
      }
    }
  }
  const int tok = (b * IMG + y) * IMG + x;
  f16 tmp[16];
  #pragma unroll
  for (int g = 0; g < 16; ++g) tmp[g] = (f16)acc[g];
  uint4* o = (uint4*)(out_tok + (size_t)tok * CH + co0);
  o[0] = *(const uint4*)(tmp);
  o[1] = *(const uint4*)(tmp + 8);
}

// ---------- kernel 2: LN1/LN2 + q/k/v projection (MFMA) + res=x+v in-place ----------
// block 256 (4 waves), Mtile = 32 tokens, N = 576 (q|k|v), K = 192
__global__ __launch_bounds__(256, 1) void ln_qkv_mfma(
    f16* __restrict__ xp, const f16* __restrict__ vp,
    const float* __restrict__ n1w, const float* __restrict__ n1b,
    const float* __restrict__ n2w, const float* __restrict__ n2b,
    const float* __restrict__ qW, const float* __restrict__ kvW,
    f16* __restrict__ qb, f16* __restrict__ kb, f16* __restrict__ vb) {
  const int tid = threadIdx.x;
  const int lane = tid & 63;
  const int wv = tid >> 6;
  const int l15 = lane & 15;
  const int quad = lane >> 4;
  const int tok0 = blockIdx.x * 32;
  __shared__ __align__(16) f16 Ax[32 * 200];
  __shared__ __align__(16) f16 Av[32 * 200];

  { // stage + LN (8 threads per token, 24 elements each)
    const int r = tid >> 3;
    const int s = tid & 7;
    const size_t gbase = (size_t)(tok0 + r) * 192 + s * 24;
    half8 hx[3], hv[3];
    const half8* px = (const half8*)(xp + gbase);
    const half8* pv = (const half8*)(vp + gbase);
    #pragma unroll
    for (int i = 0; i < 3; ++i) { hx[i] = px[i]; hv[i] = pv[i]; }
    float xv[24], vvv[24];
    float sx = 0.f, sx2 = 0.f, sv = 0.f, sv2 = 0.f;
    #pragma unroll
    for (int i = 0; i < 24; ++i) {
      xv[i] = (float)hx[i >> 3][i & 7];
      vvv[i] = (float)hv[i >> 3][i & 7];
      sx += xv[i]; sx2 += xv[i] * xv[i];
      sv += vvv[i]; sv2 += vvv[i] * vvv[i];
    }
    half8 hr[3];
    #pragma unroll
    for (int i = 0; i < 24; ++i) hr[i >> 3][i & 7] = (f16)(xv[i] + vvv[i]);
    half8* pr = (half8*)(xp + gbase);
    #pragma unroll
    for (int i = 0; i < 3; ++i) pr[i] = hr[i];   // residual, in-place
    #pragma unroll
    for (int m = 1; m < 8; m <<= 1) {
      sx += __shfl_xor(sx, m, 64); sx2 += __shfl_xor(sx2, m, 64);
      sv += __shfl_xor(sv, m, 64); sv2 += __shfl_xor(sv2, m, 64);
    }
    const float mx = sx * (1.f / 192.f);
    const float rx = rsqrtf(sx2 * (1.f / 192.f) - mx * mx + 1e-5f);
    const float mv = sv * (1.f / 192.f);
    const float rv = rsqrtf(sv2 * (1.f / 192.f) - mv * mv + 1e-5f);
    #pragma unroll
    for (int i = 0; i < 24; ++i) {
      const int c = s * 24 + i;
      Ax[r * 200 + c] = (f16)((xv[i] - mx) * rx * n1w[c] + n1b[c]);
      Av[r * 200 + c] = (f16)((vvv[i] - mv) * rv * n2w[c] + n2b[c]);
    }
  }
  __syncthreads();

  const int nb = wv * 144;
  f32x4 acc[2][9];
  #pragma unroll
  for (int mt = 0; mt < 2; ++mt)
    #pragma unroll
    for (int j = 0; j < 9; ++j) acc[mt][j] = (f32x4)0.f;

  for (int kc = 0; kc < 6; ++kc) {
    const int k = kc * 32 + quad * 8;
    const half8 ax0 = *(const half8*)(Ax + l15 * 200 + k);
    const half8 ax1 = *(const half8*)(Ax + (16 + l15) * 200 + k);
    const half8 av0 = *(const half8*)(Av + l15 * 200 + k);
    const half8 av1 = *(const half8*)(Av + (16 + l15) * 200 + k);
    #pragma unroll
    for (int j = 0; j < 9; ++j) {
      const int n0 = nb + j * 16;
      half8 b;
      if (n0 < 192) b = loadBf(qW, n0 + l15, k, 192);
      else          b = loadBf(kvW, n0 - 192 + l15, k, 192);
      if (n0 < 192) {
        acc[0][j] = mfma16(ax0, b, acc[0][j]);
        acc[1][j] = mfma16(ax1, b, acc[1][j]);
      } else {
        acc[0][j] = mfma16(av0, b, acc[0][j]);
        acc[1][j] = mfma16(av1, b, acc[1][j]);
      }
    }
  }

  // epilogue: scatter to (window, head) layout
  int wro[8];
  #pragma unroll
  for (int mt = 0; mt < 2; ++mt)
    #pragma unroll
    for (int reg = 0; reg < 4; ++reg) {
      const int tok = tok0 + mt * 16 + quad * 4 + reg;
      const int bb = tok >> 14;
      const int y = (tok >> 7) & 127;
      const int xx = tok & 127;
      const int wi = bb * 256 + ((y >> 3) << 4) + (xx >> 3);
      const int t = (y & 7) * 8 + (xx & 7);
      wro[mt * 4 + reg] = wi * 12288 + t * 24;
    }
  #pragma unroll
  for (int j = 0; j < 9; ++j) {
    const int n = nb + j * 16 + l15;
    f16* dst; int c; float scale = 1.f;
    if (n < 192)      { dst = qb; c = n;       scale = SCALE_Q; }
    else if (n < 384) { dst = kb; c = n - 192; }
    else              { dst = vb; c = n - 384; }
    const int h = c / 24;
    const int cof = h * 1536 + (c - h * 24);
    #pragma unroll
    for (int mt = 0; mt < 2; ++mt)
      #pragma unroll
      for (int reg = 0; reg < 4; ++reg)
        dst[wro[mt * 4 + reg] + cof] = (f16)(acc[mt][j][reg] * scale);
  }
}

// ---------- kernel 3: windowed attention, one block (1 wave) per (window, head) ----------
__global__ __launch_bounds__(64) void attn64(
    const f16* __restrict__ qb, const f16* __restrict__ kb,
    const f16* __restrict__ vb, const float* __restrict__ rpb,
    f16* __restrict__ fb) {
  const int wh = blockIdx.x;           // w*8 + h
  const int h = wh & 7;
  const int w = wh >> 3;
  const int t = threadIdx.x;
  __shared__ __align__(16) float ks[64 * 24];
  __shared__ __align__(16) float vs[64 * 24];
  __shared__ float bsh[225];
  const f16* kbase = kb + (size_t)wh * 1536;
  const f16* vbase = vb + (size_t)wh * 1536;
  for (int i = t; i < 1536; i += 64) { ks[i] = (float)kbase[i]; vs[i] = (float)vbase[i]; }
  for (int i = t; i < 225; i += 64) bsh[i] = rpb[i * 8 + h];
  float q[24];
  const f16* qrow = qb + ((size_t)wh * 64 + t) * 24;
  #pragma unroll
  for (int d = 0; d < 24; ++d) q[d] = (float)qrow[d];
  __syncthreads();
  const int qy = t >> 3, qx = t & 7;
  float s[64];
  float mx = -1e30f;
  #pragma unroll
  for (int kk = 0; kk < 64; ++kk) {
    float acc = 0.f;
    #pragma unroll
    for (int d = 0; d < 24; ++d) acc += q[d] * ks[kk * 24 + d];
    const int ky = kk >> 3, kx = kk & 7;
    acc += bsh[(qy - ky + 7) * 15 + (qx - kx + 7)];
    s[kk] = acc;
    mx = fmaxf(mx, acc);
  }
  float sum = 0.f;
  #pragma unroll
  for (int kk = 0; kk < 64; ++kk) { const float e = __expf(s[kk] - mx); s[kk] = e; sum += e; }
  const float inv = 1.0f / sum;
  float o[24];
  #pragma unroll
  for (int d = 0; d < 24; ++d) o[d] = 0.f;
  #pragma unroll
  for (int kk = 0; kk < 64; ++kk) {
    const float p = s[kk];
    #pragma unroll
    for (int d = 0; d < 24; ++d) o[d] += p * vs[kk * 24 + d];
  }
  f16* orow = fb + ((size_t)w * 64 + t) * 192 + h * 24;
  #pragma unroll
  for (int d = 0; d < 24; ++d) orow[d] = (f16)(o[d] * inv);
}

// ---------- kernel 4: attn-proj + LN3 (MFMA), in-place on fb (window-major) ----------
// block 256 (4 waves), Mtile = 64, N = 192, K = 192
__global__ __launch_bounds__(256, 1) void ap_ln3_mfma(
    f16* __restrict__ fb, const float* __restrict__ apW,
    const float* __restrict__ apb,
    const float* __restrict__ n3w, const float* __restrict__ n3b) {
  const int tid = threadIdx.x;
  const int lane = tid & 63;
  const int wv = tid >> 6;
  const int l15 = lane & 15;
  const int quad = lane >> 4;
  const int wt0 = blockIdx.x * 64;
  __shared__ __align__(16) f16 As[64 * 200];
  __shared__ float rs[64], rq[64];
  if (tid < 64) { rs[tid] = 0.f; rq[tid] = 0.f; }
  for (int i = tid; i < 64 * 24; i += 256) {
    const int r = i / 24, s = i - r * 24;
    *(half8*)(As + r * 200 + s * 8) = *(const half8*)(fb + (size_t)(wt0 + r) * 192 + s * 8);
  }
  __syncthreads();

  const int nb = wv * 48;
  f32x4 acc[4][3];
  #pragma unroll
  for (int mt = 0; mt < 4; ++mt)
    #pragma unroll
    for (int j = 0; j < 3; ++j) acc[mt][j] = (f32x4)0.f;

  for (int kc = 0; kc < 6; ++kc) {
    const int k = kc * 32 + quad * 8;
    half8 a[4];
    #pragma unroll
    for (int mt = 0; mt < 4; ++mt)
      a[mt] = *(const half8*)(As + (mt * 16 + l15) * 200 + k);
    #pragma unroll
    for (int j = 0; j < 3; ++j) {
      const half8 b = loadBf(apW, nb + j * 16 + l15, k, 192);
      #pragma unroll
      for (int mt = 0; mt < 4; ++mt) acc[mt][j] = mfma16(a[mt], b, acc[mt][j]);
    }
  }
  float bias[3];
  #pragma unroll
  for (int j = 0; j < 3; ++j) bias[j] = apb[nb + j * 16 + l15];
  #pragma unroll
  for (int mt = 0; mt < 4; ++mt)
    #pragma unroll
    for (int j = 0; j < 3; ++j)
      #pragma unroll
      for (int reg = 0; reg < 4; ++reg) acc[mt][j][reg] += bias[j];

  // row stats (sum over N=192): in-lane j-sum, butterfly over 16 lanes, leader adds
  float ssum[16], ssq[16];
  #pragma unroll
  for (int mt = 0; mt < 4; ++mt)
    #pragma unroll
    for (int reg = 0; reg < 4; ++reg) {
      const int i = mt * 4 + reg;
      const float a0 = acc[mt][0][reg], a1 = acc[mt][1][reg], a2 = acc[mt][2][reg];
      ssum[i] = a0 + a1 + a2;
      ssq[i] = a0 * a0 + a1 * a1 + a2 * a2;
    }
  #pragma unroll
  for (int m = 1; m < 16; m <<= 1)
    #pragma unroll
    for (int i = 0; i < 16; ++i) {
      ssum[i] += __shfl_xor(ssum[i], m, 64);
      ssq[i] += __shfl_xor(ssq[i], m, 64);
    }
  if (l15 == 0) {
    #pragma unroll
    for (int mt = 0; mt < 4; ++mt)
      #pragma unroll
      for (int reg = 0; reg < 4; ++reg) {
        const int row = mt * 16 + quad * 4 + reg;
        atomicAdd(&rs[row], ssum[mt * 4 + reg]);
        atomicAdd(&rq[row], ssq[mt * 4 + reg]);
      }
  }
  __syncthreads();

  float w3[3], b3[3]; int cc[3];
  #pragma unroll
  for (int j = 0; j < 3; ++j) {
    cc[j] = nb + j * 16 + l15;
    w3[j] = n3w[cc[j]]; b3[j] = n3b[cc[j]];
  }
  #pragma unroll
  for (int mt = 0; mt < 4; ++mt)
    #pragma unroll
    for (int reg = 0; reg < 4; ++reg) {
      const int row = mt * 16 + quad * 4 + reg;
      const float mean = rs[row] * (1.f / 192.f);
      const float rstd = rsqrtf(rq[row] * (1.f / 192.f) - mean * mean + 1e-5f);
      #pragma unroll
      for (int j = 0; j < 3; ++j)
        fb[(size_t)(wt0 + row) * 192 + cc[j]] =
            (f16)((acc[mt][j][reg] - mean) * rstd * w3[j] + b3[j]);
    }
}

// ---------- kernel 5: fc1+GELU+fc2+x2+LN4+residual+NCHW (MFMA, fused MLP) ----------
// block 256 (4 waves), Mtile = 32 (window-major rows)
__global__ __launch_bounds__(256, 1) void mlp_mfma(
    const f16* __restrict__ m, const float* __restrict__ w1,
    const float* __restrict__ b1, const float* __restrict__ w2,
    const float* __restrict__ b2,
    const float* __restrict__ n4w, const float* __restrict__ n4b,
    const f16* __restrict__ res, float* __restrict__ out) {
  const int tid = threadIdx.x;
  const int lane = tid & 63;
  const int wv = tid >> 6;
  const int l15 = lane & 15;
  const int quad = lane >> 4;
  const int wt0 = blockIdx.x * 32;
  __shared__ __align__(16) f16 As[32 * 200];
  __shared__ __align__(16) f16 Hs[32 * 776];
  __shared__ float rs[32], rq[32];
  if (tid < 32) { rs[tid] = 0.f; rq[tid] = 0.f; }
  for (int i = tid; i < 32 * 24; i += 256) {
    const int r = i / 24, s = i - r * 24;
    *(half8*)(As + r * 200 + s * 8) = *(const half8*)(m + (size_t)(wt0 + r) * 192 + s * 8);
  }
  __syncthreads();

  // fc1: N-slice 192 per wave
  const int nb1 = wv * 192;
  f32x4 acc1[2][12];
  #pragma unroll
  for (int mt = 0; mt < 2; ++mt)
    #pragma unroll
    for (int j = 0; j < 12; ++j) acc1[mt][j] = (f32x4)0.f;
  for (int kc = 0; kc < 6; ++kc) {
    const int k = kc * 32 + quad * 8;
    const half8 a0 = *(const half8*)(As + l15 * 200 + k);
    const half8 a1 = *(const half8*)(As + (16 + l15) * 200 + k);
    #pragma unroll
    for (int j = 0; j < 12; ++j) {
      const half8 b = loadBf(w1, nb1 + j * 16 + l15, k, 192);
      acc1[0][j] = mfma16(a0, b, acc1[0][j]);
      acc1[1][j] = mfma16(a1, b, acc1[1][j]);
    }
  }
  #pragma unroll
  for (int j = 0; j < 12; ++j) {
    const int n = nb1 + j * 16 + l15;
    const float bj = b1[n];
    #pragma unroll
    for (int mt = 0; mt < 2; ++mt)
      #pragma unroll
      for (int reg = 0; reg < 4; ++reg) {
        const int row = mt * 16 + quad * 4 + reg;
        Hs[row * 776 + n] = (f16)gelu(acc1[mt][j][reg] + bj);
      }
  }
  __syncthreads();

  // fc2: K = 768, N-slice 48 per wave
  const int nb2 = wv * 48;
  f32x4 acc2[2][3];
  #pragma unroll
  for (int mt = 0; mt < 2; ++mt)
    #pragma unroll
    for (int j = 0; j < 3; ++j) acc2[mt][j] = (f32x4)0.f;
  for (int kc = 0; kc < 24; ++kc) {
    const int k = kc * 32 + quad * 8;
    const half8 a0 = *(const half8*)(Hs + l15 * 776 + k);
    const half8 a1 = *(const half8*)(Hs + (16 + l15) * 776 + k);
    #pragma unroll
    for (int j = 0; j < 3; ++j) {
      const half8 b = loadBf(w2, nb2 + j * 16 + l15, k, 768);
      acc2[0][j] = mfma16(a0, b, acc2[0][j]);
      acc2[1][j] = mfma16(a1, b, acc2[1][j]);
    }
  }
  int cc[3]; float w4[3], b4[3];
  #pragma unroll
  for (int j = 0; j < 3; ++j) {
    cc[j] = nb2 + j * 16 + l15;
    const float bj = b2[cc[j]];
    w4[j] = n4w[cc[j]]; b4[j] = n4b[cc[j]];
    #pragma unroll
    for (int mt = 0; mt < 2; ++mt)
      #pragma unroll
      for (int reg = 0; reg < 4; ++reg)
        acc2[mt][j][reg] = 2.f * (acc2[mt][j][reg] + bj);   // m = m + m
  }
  // LN4 row stats
  float ssum[8], ssq[8];
  #pragma unroll
  for (int mt = 0; mt < 2; ++mt)
    #pragma unroll
    for (int reg = 0; reg < 4; ++reg) {
      const int i = mt * 4 + reg;
      const float a0 = acc2[mt][0][reg], a1 = acc2[mt][1][reg], a2 = acc2[mt][2][reg];
      ssum[i] = a0 + a1 + a2;
      ssq[i] = a0 * a0 + a1 * a1 + a2 * a2;
    }
  #pragma unroll
  for (int mm = 1; mm < 16; mm <<= 1)
    #pragma unroll
    for (int i = 0; i < 8; ++i) {
      ssum[i] += __shfl_xor(ssum[i], mm, 64);
      ssq[i] += __shfl_xor(ssq[i], mm, 64);
    }
  if (l15 == 0) {
    #pragma unroll
    for (int mt = 0; mt < 2; ++mt)
      #pragma unroll
      for (int reg = 0; reg < 4; ++reg) {
        const int row = mt * 16 + quad * 4 + reg;
        atomicAdd(&rs[row], ssum[mt * 4 + reg]);
        atomicAdd(&rq[row], ssq[mt * 4 + reg]);
      }
  }
  __syncthreads();

  // normalize + residual + NCHW store (float4 over 4 consecutive tokens)
  const int wi = wt0 >> 6;
  const int t_base = wt0 & 63;
  const int b_img = wi >> 8;
  const int wy = (wi >> 4) & 15;
  const int wx = wi & 15;
  #pragma unroll
  for (int mt = 0; mt < 2; ++mt) {
    const int row0 = mt * 16 + quad * 4;
    const int t0 = t_base + row0;
    const int y = wy * 8 + (t0 >> 3);
    const int x0 = wx * 8 + (t0 & 7);
    float mean[4], rstd[4];
    #pragma unroll
    for (int reg = 0; reg < 4; ++reg) {
      const int row = row0 + reg;
      mean[reg] = rs[row] * (1.f / 192.f);
      rstd[reg] = rsqrtf(rq[row] * (1.f / 192.f) - mean[reg] * mean[reg] + 1e-5f);
    }
    const size_t tokbase = ((size_t)(b_img * 128 + y)) * 128 + x0;  // token index of reg 0
    #pragma unroll
    for (int j = 0; j < 3; ++j) {
      float4 o;
      float vals[4];
      #pragma unroll
      for (int reg = 0; reg < 4; ++reg) {
        const float rr = (float)res[(tokbase + reg) * 192 + cc[j]];
        vals[reg] = (acc2[mt][j][reg] - mean[reg]) * rstd[reg] * w4[j] + b4[j] + rr;
      }
      o.x = vals[0]; o.y = vals[1]; o.z = vals[2]; o.w = vals[3];
      float* dst = out + ((size_t)(b_img * 192 + cc[j])) * 16384 + (y * 128 + x0);
      *(float4*)dst = o;
    }
  }
}

extern "C" void kernel_launch(void* const* d_in, const int* in_sizes, int n_in,
                              void* d_out, int out_size, void* d_ws, size_t ws_size,
                              hipStream_t stream) {
  (void)in_sizes; (void)n_in; (void)out_size; (void)ws_size;
  const float* x    = (const float*)d_in[0];
  const float* v    = (const float*)d_in[1];
  const float* pq_w = (const float*)d_in[2];
  const float* pq_b = (const float*)d_in[3];
  const float* pv_w = (const float*)d_in[4];
  const float* pv_b = (const float*)d_in[5];
  const float* n1w  = (const float*)d_in[6];
  const float* n1b  = (const float*)d_in[7];
  const float* n2w  = (const float*)d_in[8];
  const float* n2b  = (const float*)d_in[9];
  const float* n3w  = (const float*)d_in[10];
  const float* n3b  = (const float*)d_in[11];
  const float* n4w  = (const float*)d_in[12];
  const float* n4b  = (const float*)d_in[13];
  const float* qW   = (const float*)d_in[14];
  const float* kvW  = (const float*)d_in[15];
  const float* apW  = (const float*)d_in[16];
  const float* apb  = (const float*)d_in[17];
  const float* rpb  = (const float*)d_in[18];
  const float* w1   = (const float*)d_in[19];
  const float* b1   = (const float*)d_in[20];
  const float* w2   = (const float*)d_in[21];
  const float* b2   = (const float*)d_in[22];
  float* out = (float*)d_out;

  // Workspace: 3 f16 half-slots (151 MB total). q/k live in d_out (exact fit),
  // both dead before the final kernel overwrites every element of d_out.
  const size_t HE = 25165824;           // elements per half-slot (tokens*192)
  f16* xp   = (f16*)d_ws;               // conv(x) -> res (in-place in ln_qkv)
  f16* vp   = xp + HE;                  // conv(v) -> fb (attn out) -> m (LN3, in-place)
  f16* vvb  = vp + HE;                  // v projection
  f16* qb   = (f16*)d_out;              // q (scratch in d_out)
  f16* kb   = qb + HE;                  // k (scratch in d_out)
  f16* fb   = vp;                       // alias: vp dead after ln_qkv

  conv3x3_tok<<<12288, 128, 0, stream>>>(x, pq_w, pq_b, xp);
  conv3x3_tok<<<12288, 128, 0, stream>>>(v, pv_w, pv_b, vp);
  ln_qkv_mfma<<<4096, 256, 0, stream>>>(xp, vp, n1w, n1b, n2w, n2b, qW, kvW, qb, kb, vvb);
  attn64<<<16384, 64, 0, stream>>>(qb, kb, vvb, rpb, fb);
  ap_ln3_mfma<<<2048, 256, 0, stream>>>(fb, apW, apb, n3w, n3b);
  mlp_mfma<<<4096, 256, 0, stream>>>(fb, w1, b1, w2, b2, n4w, n4b, xp, out);
}

// Round 4
// 1779.550 us; speedup vs baseline: 5.4856x; 2.7895x over previous
//
#include <hip/hip_runtime.h>
#include <hip/hip_bf16.h>
#include <math.h>

typedef _Float16 f16;
typedef _Float16 half8 __attribute__((ext_vector_type(8)));
typedef float f32x4 __attribute__((ext_vector_type(4)));

#define IMG 128
#define CIN 96
#define CH  192
#define SCALE_Q 0.2041241452319315f   // 24^-0.5

__device__ __forceinline__ f32x4 mfma16(half8 a, half8 b, f32x4 c) {
  return __builtin_amdgcn_mfma_f32_16x16x32_f16(a, b, c, 0, 0, 0);
}

// load 8 consecutive K-elements of weight row `row` (fp32, row-major [N][K]) -> f16 frag
__device__ __forceinline__ half8 loadBf(const float* __restrict__ W, int row, int k, int ldk) {
  const float* p = W + (size_t)row * ldk + k;
  const float4 a = *(const float4*)p;
  const float4 b = *(const float4*)(p + 4);
  half8 h;
  h[0] = (f16)a.x; h[1] = (f16)a.y; h[2] = (f16)a.z; h[3] = (f16)a.w;
  h[4] = (f16)b.x; h[5] = (f16)b.y; h[6] = (f16)b.z; h[7] = (f16)b.w;
  return h;
}

// exact-GELU via Abramowitz-Stegun erf approx (|err| <= 1.5e-7)
__device__ __forceinline__ float gelu(float x) {
  const float u = 0.70710678118654752f * x;
  const float a = fabsf(u);
  const float t = 1.0f / (1.0f + 0.3275911f * a);
  const float poly = t * (0.254829592f + t * (-0.284496736f +
                     t * (1.421413741f + t * (-1.453152027f + t * 1.061405429f))));
  float er = 1.0f - poly * __expf(-u * u);
  er = (u < 0.f) ? -er : er;
  return 0.5f * x * (1.0f + er);
}

// ---------- kernel 0: reorder conv weights OIHW fp32 -> [co][(ky*3+kx)*96+ci] f16 ----------
__global__ __launch_bounds__(256) void reorder_w(
    const float* __restrict__ pq_w, const float* __restrict__ pv_w,
    f16* __restrict__ Wr) {
  const int i = blockIdx.x * 256 + threadIdx.x;   // over 2*192*864
  if (i >= 2 * 192 * 864) return;
  const int which = i / (192 * 864);
  const int rem = i - which * (192 * 864);
  const int co = rem / 864;
  const int kk = rem - co * 864;
  const int s = kk / 96;           // ky*3+kx
  const int ci = kk - s * 96;
  const float* src = which ? pv_w : pq_w;
  Wr[i] = (f16)src[co * 864 + ci * 9 + s];
}

// ---------- kernel 1: implicit-GEMM MFMA 3x3 conv, both tensors in one grid ----------
// grid 4096 = {which(2)} x {b(8)} x {y(128)} x {xseg(2)}; block 256 (4 waves)
// M = 64 pixels (half row), N = 192, K = 9*96 (9 shifts x 3 MFMA K-steps)
__global__ __launch_bounds__(256, 1) void conv3x3_mfma(
    const float* __restrict__ xin, const float* __restrict__ vin,
    const f16* __restrict__ Wr,
    const float* __restrict__ pq_b, const float* __restrict__ pv_b,
    f16* __restrict__ xp, f16* __restrict__ vp) {
  int bz = blockIdx.x;
  const int which = bz >> 11; bz &= 2047;
  const int b = bz >> 8;
  const int y = (bz >> 1) & 127;
  const int xseg = bz & 1;
  const int x0 = xseg * 64;
  const float* in = which ? vin : xin;
  const float* bias = which ? pv_b : pq_b;
  const f16* W = Wr + (size_t)which * 192 * 864;
  f16* out = which ? vp : xp;

  // im2col halo tile: [r(3)][x(66)][c(96)], pixel stride padded 96->104
  __shared__ __align__(16) f16 ST[3 * 66 * 104];
  const int tid = threadIdx.x;
  for (int i = tid; i < 3 * 96 * 66; i += 256) {
    const int r = i / (96 * 66);
    const int rem2 = i - r * (96 * 66);
    const int c = rem2 / 66;
    const int xx = rem2 - c * 66;
    const int gy = y + r - 1;
    const int gx = x0 - 1 + xx;
    float val = 0.f;
    if (gy >= 0 && gy < IMG && gx >= 0 && gx < IMG)
      val = in[(((size_t)b * CIN + c) * IMG + gy) * IMG + gx];
    ST[(r * 66 + xx) * 104 + c] = (f16)val;
  }
  __syncthreads();

  const int lane = tid & 63;
  const int wv = tid >> 6;
  const int l15 = lane & 15;
  const int quad = lane >> 4;
  const int nb = wv * 48;          // N-slice 48 per wave

  f32x4 acc[4][3];
  #pragma unroll
  for (int mt = 0; mt < 4; ++mt)
    #pragma unroll
    for (int j = 0; j < 3; ++j) acc[mt][j] = (f32x4)0.f;

  #pragma unroll
  for (int s = 0; s < 9; ++s) {
    const int ky = s / 3, kx = s - ky * 3;
    #pragma unroll
    for (int kstep = 0; kstep < 3; ++kstep) {
      const int k = kstep * 32 + quad * 8;   // ci offset
      half8 a[4];
      #pragma unroll
      for (int mt = 0; mt < 4; ++mt)
        a[mt] = *(const half8*)(ST + ((ky * 66) + (mt * 16 + l15) + kx) * 104 + k);
      #pragma unroll
      for (int j = 0; j < 3; ++j) {
        const half8 bf = *(const half8*)(W + (size_t)(nb + j * 16 + l15) * 864 + s * 96 + k);
        #pragma unroll
        for (int mt = 0; mt < 4; ++mt) acc[mt][j] = mfma16(a[mt], bf, acc[mt][j]);
      }
    }
  }

  const int tok0 = (b * IMG + y) * IMG + x0;
  #pragma unroll
  for (int j = 0; j < 3; ++j) {
    const int n = nb + j * 16 + l15;
    const float bn = bias[n];
    #pragma unroll
    for (int mt = 0; mt < 4; ++mt)
      #pragma unroll
      for (int reg = 0; reg < 4; ++reg) {
        const int m = mt * 16 + quad * 4 + reg;
        out[(size_t)(tok0 + m) * CH + n] = (f16)(acc[mt][j][reg] + bn);
      }
  }
}

// ---------- kernel 2: LN1/LN2 + q/k/v projection (MFMA) + res=x+v in-place ----------
// block 256 (4 waves), Mtile = 32 tokens, N = 576 (q|k|v), K = 192
__global__ __launch_bounds__(256, 1) void ln_qkv_mfma(
    f16* __restrict__ xp, const f16* __restrict__ vp,
    const float* __restrict__ n1w, const float* __restrict__ n1b,
    const float* __restrict__ n2w, const float* __restrict__ n2b,
    const float* __restrict__ qW, const float* __restrict__ kvW,
    f16* __restrict__ qb, f16* __restrict__ kb, f16* __restrict__ vb) {
  const int tid = threadIdx.x;
  const int lane = tid & 63;
  const int wv = tid >> 6;
  const int l15 = lane & 15;
  const int quad = lane >> 4;
  const int tok0 = blockIdx.x * 32;
  __shared__ __align__(16) f16 Ax[32 * 200];
  __shared__ __align__(16) f16 Av[32 * 200];

  { // stage + LN (8 threads per token, 24 elements each)
    const int r = tid >> 3;
    const int s = tid & 7;
    const size_t gbase = (size_t)(tok0 + r) * 192 + s * 24;
    half8 hx[3], hv[3];
    const half8* px = (const half8*)(xp + gbase);
    const half8* pv = (const half8*)(vp + gbase);
    #pragma unroll
    for (int i = 0; i < 3; ++i) { hx[i] = px[i]; hv[i] = pv[i]; }
    float xv[24], vvv[24];
    float sx = 0.f, sx2 = 0.f, sv = 0.f, sv2 = 0.f;
    #pragma unroll
    for (int i = 0; i < 24; ++i) {
      xv[i] = (float)hx[i >> 3][i & 7];
      vvv[i] = (float)hv[i >> 3][i & 7];
      sx += xv[i]; sx2 += xv[i] * xv[i];
      sv += vvv[i]; sv2 += vvv[i] * vvv[i];
    }
    half8 hr[3];
    #pragma unroll
    for (int i = 0; i < 24; ++i) hr[i >> 3][i & 7] = (f16)(xv[i] + vvv[i]);
    half8* pr = (half8*)(xp + gbase);
    #pragma unroll
    for (int i = 0; i < 3; ++i) pr[i] = hr[i];   // residual, in-place
    #pragma unroll
    for (int m = 1; m < 8; m <<= 1) {
      sx += __shfl_xor(sx, m, 64); sx2 += __shfl_xor(sx2, m, 64);
      sv += __shfl_xor(sv, m, 64); sv2 += __shfl_xor(sv2, m, 64);
    }
    const float mx = sx * (1.f / 192.f);
    const float rx = rsqrtf(sx2 * (1.f / 192.f) - mx * mx + 1e-5f);
    const float mv = sv * (1.f / 192.f);
    const float rv = rsqrtf(sv2 * (1.f / 192.f) - mv * mv + 1e-5f);
    #pragma unroll
    for (int i = 0; i < 24; ++i) {
      const int c = s * 24 + i;
      Ax[r * 200 + c] = (f16)((xv[i] - mx) * rx * n1w[c] + n1b[c]);
      Av[r * 200 + c] = (f16)((vvv[i] - mv) * rv * n2w[c] + n2b[c]);
    }
  }
  __syncthreads();

  const int nb = wv * 144;
  f32x4 acc[2][9];
  #pragma unroll
  for (int mt = 0; mt < 2; ++mt)
    #pragma unroll
    for (int j = 0; j < 9; ++j) acc[mt][j] = (f32x4)0.f;

  for (int kc = 0; kc < 6; ++kc) {
    const int k = kc * 32 + quad * 8;
    const half8 ax0 = *(const half8*)(Ax + l15 * 200 + k);
    const half8 ax1 = *(const half8*)(Ax + (16 + l15) * 200 + k);
    const half8 av0 = *(const half8*)(Av + l15 * 200 + k);
    const half8 av1 = *(const half8*)(Av + (16 + l15) * 200 + k);
    #pragma unroll
    for (int j = 0; j < 9; ++j) {
      const int n0 = nb + j * 16;
      half8 b;
      if (n0 < 192) b = loadBf(qW, n0 + l15, k, 192);
      else          b = loadBf(kvW, n0 - 192 + l15, k, 192);
      if (n0 < 192) {
        acc[0][j] = mfma16(ax0, b, acc[0][j]);
        acc[1][j] = mfma16(ax1, b, acc[1][j]);
      } else {
        acc[0][j] = mfma16(av0, b, acc[0][j]);
        acc[1][j] = mfma16(av1, b, acc[1][j]);
      }
    }
  }

  // epilogue: scatter to (window, head) layout
  int wro[8];
  #pragma unroll
  for (int mt = 0; mt < 2; ++mt)
    #pragma unroll
    for (int reg = 0; reg < 4; ++reg) {
      const int tok = tok0 + mt * 16 + quad * 4 + reg;
      const int bb = tok >> 14;
      const int y = (tok >> 7) & 127;
      const int xx = tok & 127;
      const int wi = bb * 256 + ((y >> 3) << 4) + (xx >> 3);
      const int t = (y & 7) * 8 + (xx & 7);
      wro[mt * 4 + reg] = wi * 12288 + t * 24;
    }
  #pragma unroll
  for (int j = 0; j < 9; ++j) {
    const int n = nb + j * 16 + l15;
    f16* dst; int c; float scale = 1.f;
    if (n < 192)      { dst = qb; c = n;       scale = SCALE_Q; }
    else if (n < 384) { dst = kb; c = n - 192; }
    else              { dst = vb; c = n - 384; }
    const int h = c / 24;
    const int cof = h * 1536 + (c - h * 24);
    #pragma unroll
    for (int mt = 0; mt < 2; ++mt)
      #pragma unroll
      for (int reg = 0; reg < 4; ++reg)
        dst[wro[mt * 4 + reg] + cof] = (f16)(acc[mt][j][reg] * scale);
  }
}

// ---------- kernel 3: windowed attention, one block (1 wave) per (window, head) ----------
__global__ __launch_bounds__(64) void attn64(
    const f16* __restrict__ qb, const f16* __restrict__ kb,
    const f16* __restrict__ vb, const float* __restrict__ rpb,
    f16* __restrict__ fb) {
  const int wh = blockIdx.x;           // w*8 + h
  const int h = wh & 7;
  const int w = wh >> 3;
  const int t = threadIdx.x;
  __shared__ __align__(16) float ks[64 * 24];
  __shared__ __align__(16) float vs[64 * 24];
  __shared__ float bsh[225];
  const f16* kbase = kb + (size_t)wh * 1536;
  const f16* vbase = vb + (size_t)wh * 1536;
  for (int i = t; i < 1536; i += 64) { ks[i] = (float)kbase[i]; vs[i] = (float)vbase[i]; }
  for (int i = t; i < 225; i += 64) bsh[i] = rpb[i * 8 + h];
  float q[24];
  const f16* qrow = qb + ((size_t)wh * 64 + t) * 24;
  #pragma unroll
  for (int d = 0; d < 24; ++d) q[d] = (float)qrow[d];
  __syncthreads();
  const int qy = t >> 3, qx = t & 7;
  float s[64];
  float mx = -1e30f;
  #pragma unroll
  for (int kk = 0; kk < 64; ++kk) {
    float acc = 0.f;
    #pragma unroll
    for (int d = 0; d < 24; ++d) acc += q[d] * ks[kk * 24 + d];
    const int ky = kk >> 3, kx = kk & 7;
    acc += bsh[(qy - ky + 7) * 15 + (qx - kx + 7)];
    s[kk] = acc;
    mx = fmaxf(mx, acc);
  }
  float sum = 0.f;
  #pragma unroll
  for (int kk = 0; kk < 64; ++kk) { const float e = __expf(s[kk] - mx); s[kk] = e; sum += e; }
  const float inv = 1.0f / sum;
  float o[24];
  #pragma unroll
  for (int d = 0; d < 24; ++d) o[d] = 0.f;
  #pragma unroll
  for (int kk = 0; kk < 64; ++kk) {
    const float p = s[kk];
    #pragma unroll
    for (int d = 0; d < 24; ++d) o[d] += p * vs[kk * 24 + d];
  }
  f16* orow = fb + ((size_t)w * 64 + t) * 192 + h * 24;
  #pragma unroll
  for (int d = 0; d < 24; ++d) orow[d] = (f16)(o[d] * inv);
}

// ---------- kernel 4: attn-proj + LN3 (MFMA), in-place on fb (window-major) ----------
__global__ __launch_bounds__(256, 1) void ap_ln3_mfma(
    f16* __restrict__ fb, const float* __restrict__ apW,
    const float* __restrict__ apb,
    const float* __restrict__ n3w, const float* __restrict__ n3b) {
  const int tid = threadIdx.x;
  const int lane = tid & 63;
  const int wv = tid >> 6;
  const int l15 = lane & 15;
  const int quad = lane >> 4;
  const int wt0 = blockIdx.x * 64;
  __shared__ __align__(16) f16 As[64 * 200];
  __shared__ float rs[64], rq[64];
  if (tid < 64) { rs[tid] = 0.f; rq[tid] = 0.f; }
  for (int i = tid; i < 64 * 24; i += 256) {
    const int r = i / 24, s = i - r * 24;
    *(half8*)(As + r * 200 + s * 8) = *(const half8*)(fb + (size_t)(wt0 + r) * 192 + s * 8);
  }
  __syncthreads();

  const int nb = wv * 48;
  f32x4 acc[4][3];
  #pragma unroll
  for (int mt = 0; mt < 4; ++mt)
    #pragma unroll
    for (int j = 0; j < 3; ++j) acc[mt][j] = (f32x4)0.f;

  for (int kc = 0; kc < 6; ++kc) {
    const int k = kc * 32 + quad * 8;
    half8 a[4];
    #pragma unroll
    for (int mt = 0; mt < 4; ++mt)
      a[mt] = *(const half8*)(As + (mt * 16 + l15) * 200 + k);
    #pragma unroll
    for (int j = 0; j < 3; ++j) {
      const half8 b = loadBf(apW, nb + j * 16 + l15, k, 192);
      #pragma unroll
      for (int mt = 0; mt < 4; ++mt) acc[mt][j] = mfma16(a[mt], b, acc[mt][j]);
    }
  }
  float bias[3];
  #pragma unroll
  for (int j = 0; j < 3; ++j) bias[j] = apb[nb + j * 16 + l15];
  #pragma unroll
  for (int mt = 0; mt < 4; ++mt)
    #pragma unroll
    for (int j = 0; j < 3; ++j)
      #pragma unroll
      for (int reg = 0; reg < 4; ++reg) acc[mt][j][reg] += bias[j];

  float ssum[16], ssq[16];
  #pragma unroll
  for (int mt = 0; mt < 4; ++mt)
    #pragma unroll
    for (int reg = 0; reg < 4; ++reg) {
      const int i = mt * 4 + reg;
      const float a0 = acc[mt][0][reg], a1 = acc[mt][1][reg], a2 = acc[mt][2][reg];
      ssum[i] = a0 + a1 + a2;
      ssq[i] = a0 * a0 + a1 * a1 + a2 * a2;
    }
  #pragma unroll
  for (int m = 1; m < 16; m <<= 1)
    #pragma unroll
    for (int i = 0; i < 16; ++i) {
      ssum[i] += __shfl_xor(ssum[i], m, 64);
      ssq[i] += __shfl_xor(ssq[i], m, 64);
    }
  if (l15 == 0) {
    #pragma unroll
    for (int mt = 0; mt < 4; ++mt)
      #pragma unroll
      for (int reg = 0; reg < 4; ++reg) {
        const int row = mt * 16 + quad * 4 + reg;
        atomicAdd(&rs[row], ssum[mt * 4 + reg]);
        atomicAdd(&rq[row], ssq[mt * 4 + reg]);
      }
  }
  __syncthreads();

  float w3[3], b3[3]; int cc[3];
  #pragma unroll
  for (int j = 0; j < 3; ++j) {
    cc[j] = nb + j * 16 + l15;
    w3[j] = n3w[cc[j]]; b3[j] = n3b[cc[j]];
  }
  #pragma unroll
  for (int mt = 0; mt < 4; ++mt)
    #pragma unroll
    for (int reg = 0; reg < 4; ++reg) {
      const int row = mt * 16 + quad * 4 + reg;
      const float mean = rs[row] * (1.f / 192.f);
      const float rstd = rsqrtf(rq[row] * (1.f / 192.f) - mean * mean + 1e-5f);
      #pragma unroll
      for (int j = 0; j < 3; ++j)
        fb[(size_t)(wt0 + row) * 192 + cc[j]] =
            (f16)((acc[mt][j][reg] - mean) * rstd * w3[j] + b3[j]);
    }
}

// ---------- kernel 5: fc1+GELU+fc2+x2+LN4+residual+NCHW (MFMA, fused MLP) ----------
__global__ __launch_bounds__(256, 1) void mlp_mfma(
    const f16* __restrict__ m, const float* __restrict__ w1,
    const float* __restrict__ b1, const float* __restrict__ w2,
    const float* __restrict__ b2,
    const float* __restrict__ n4w, const float* __restrict__ n4b,
    const f16* __restrict__ res, float* __restrict__ out) {
  const int tid = threadIdx.x;
  const int lane = tid & 63;
  const int wv = tid >> 6;
  const int l15 = lane & 15;
  const int quad = lane >> 4;
  const int wt0 = blockIdx.x * 32;
  __shared__ __align__(16) f16 As[32 * 200];
  __shared__ __align__(16) f16 Hs[32 * 776];
  __shared__ float rs[32], rq[32];
  if (tid < 32) { rs[tid] = 0.f; rq[tid] = 0.f; }
  for (int i = tid; i < 32 * 24; i += 256) {
    const int r = i / 24, s = i - r * 24;
    *(half8*)(As + r * 200 + s * 8) = *(const half8*)(m + (size_t)(wt0 + r) * 192 + s * 8);
  }
  __syncthreads();

  const int nb1 = wv * 192;
  f32x4 acc1[2][12];
  #pragma unroll
  for (int mt = 0; mt < 2; ++mt)
    #pragma unroll
    for (int j = 0; j < 12; ++j) acc1[mt][j] = (f32x4)0.f;
  for (int kc = 0; kc < 6; ++kc) {
    const int k = kc * 32 + quad * 8;
    const half8 a0 = *(const half8*)(As + l15 * 200 + k);
    const half8 a1 = *(const half8*)(As + (16 + l15) * 200 + k);
    #pragma unroll
    for (int j = 0; j < 12; ++j) {
      const half8 b = loadBf(w1, nb1 + j * 16 + l15, k, 192);
      acc1[0][j] = mfma16(a0, b, acc1[0][j]);
      acc1[1][j] = mfma16(a1, b, acc1[1][j]);
    }
  }
  #pragma unroll
  for (int j = 0; j < 12; ++j) {
    const int n = nb1 + j * 16 + l15;
    const float bj = b1[n];
    #pragma unroll
    for (int mt = 0; mt < 2; ++mt)
      #pragma unroll
      for (int reg = 0; reg < 4; ++reg) {
        const int row = mt * 16 + quad * 4 + reg;
        Hs[row * 776 + n] = (f16)gelu(acc1[mt][j][reg] + bj);
      }
  }
  __syncthreads();

  const int nb2 = wv * 48;
  f32x4 acc2[2][3];
  #pragma unroll
  for (int mt = 0; mt < 2; ++mt)
    #pragma unroll
    for (int j = 0; j < 3; ++j) acc2[mt][j] = (f32x4)0.f;
  for (int kc = 0; kc < 24; ++kc) {
    const int k = kc * 32 + quad * 8;
    const half8 a0 = *(const half8*)(Hs + l15 * 776 + k);
    const half8 a1 = *(const half8*)(Hs + (16 + l15) * 776 + k);
    #pragma unroll
    for (int j = 0; j < 3; ++j) {
      const half8 b = loadBf(w2, nb2 + j * 16 + l15, k, 768);
      acc2[0][j] = mfma16(a0, b, acc2[0][j]);
      acc2[1][j] = mfma16(a1, b, acc2[1][j]);
    }
  }
  int cc[3]; float w4[3], b4[3];
  #pragma unroll
  for (int j = 0; j < 3; ++j) {
    cc[j] = nb2 + j * 16 + l15;
    const float bj = b2[cc[j]];
    w4[j] = n4w[cc[j]]; b4[j] = n4b[cc[j]];
    #pragma unroll
    for (int mt = 0; mt < 2; ++mt)
      #pragma unroll
      for (int reg = 0; reg < 4; ++reg)
        acc2[mt][j][reg] = 2.f * (acc2[mt][j][reg] + bj);   // m = m + m
  }
  float ssum[8], ssq[8];
  #pragma unroll
  for (int mt = 0; mt < 2; ++mt)
    #pragma unroll
    for (int reg = 0; reg < 4; ++reg) {
      const int i = mt * 4 + reg;
      const float a0 = acc2[mt][0][reg], a1 = acc2[mt][1][reg], a2 = acc2[mt][2][reg];
      ssum[i] = a0 + a1 + a2;
      ssq[i] = a0 * a0 + a1 * a1 + a2 * a2;
    }
  #pragma unroll
  for (int mm = 1; mm < 16; mm <<= 1)
    #pragma unroll
    for (int i = 0; i < 8; ++i) {
      ssum[i] += __shfl_xor(ssum[i], mm, 64);
      ssq[i] += __shfl_xor(ssq[i], mm, 64);
    }
  if (l15 == 0) {
    #pragma unroll
    for (int mt = 0; mt < 2; ++mt)
      #pragma unroll
      for (int reg = 0; reg < 4; ++reg) {
        const int row = mt * 16 + quad * 4 + reg;
        atomicAdd(&rs[row], ssum[mt * 4 + reg]);
        atomicAdd(&rq[row], ssq[mt * 4 + reg]);
      }
  }
  __syncthreads();

  const int wi = wt0 >> 6;
  const int t_base = wt0 & 63;
  const int b_img = wi >> 8;
  const int wy = (wi >> 4) & 15;
  const int wx = wi & 15;
  #pragma unroll
  for (int mt = 0; mt < 2; ++mt) {
    const int row0 = mt * 16 + quad * 4;
    const int t0 = t_base + row0;
    const int y = wy * 8 + (t0 >> 3);
    const int x0 = wx * 8 + (t0 & 7);
    float mean[4], rstd[4];
    #pragma unroll
    for (int reg = 0; reg < 4; ++reg) {
      const int row = row0 + reg;
      mean[reg] = rs[row] * (1.f / 192.f);
      rstd[reg] = rsqrtf(rq[row] * (1.f / 192.f) - mean[reg] * mean[reg] + 1e-5f);
    }
    const size_t tokbase = ((size_t)(b_img * 128 + y)) * 128 + x0;
    #pragma unroll
    for (int j = 0; j < 3; ++j) {
      float4 o;
      float vals[4];
      #pragma unroll
      for (int reg = 0; reg < 4; ++reg) {
        const float rr = (float)res[(tokbase + reg) * 192 + cc[j]];
        vals[reg] = (acc2[mt][j][reg] - mean[reg]) * rstd[reg] * w4[j] + b4[j] + rr;
      }
      o.x = vals[0]; o.y = vals[1]; o.z = vals[2]; o.w = vals[3];
      float* dst = out + ((size_t)(b_img * 192 + cc[j])) * 16384 + (y * 128 + x0);
      *(float4*)dst = o;
    }
  }
}

extern "C" void kernel_launch(void* const* d_in, const int* in_sizes, int n_in,
                              void* d_out, int out_size, void* d_ws, size_t ws_size,
                              hipStream_t stream) {
  (void)in_sizes; (void)n_in; (void)out_size; (void)ws_size;
  const float* x    = (const float*)d_in[0];
  const float* v    = (const float*)d_in[1];
  const float* pq_w = (const float*)d_in[2];
  const float* pq_b = (const float*)d_in[3];
  const float* pv_w = (const float*)d_in[4];
  const float* pv_b = (const float*)d_in[5];
  const float* n1w  = (const float*)d_in[6];
  const float* n1b  = (const float*)d_in[7];
  const float* n2w  = (const float*)d_in[8];
  const float* n2b  = (const float*)d_in[9];
  const float* n3w  = (const float*)d_in[10];
  const float* n3b  = (const float*)d_in[11];
  const float* n4w  = (const float*)d_in[12];
  const float* n4b  = (const float*)d_in[13];
  const float* qW   = (const float*)d_in[14];
  const float* kvW  = (const float*)d_in[15];
  const float* apW  = (const float*)d_in[16];
  const float* apb  = (const float*)d_in[17];
  const float* rpb  = (const float*)d_in[18];
  const float* w1   = (const float*)d_in[19];
  const float* b1   = (const float*)d_in[20];
  const float* w2   = (const float*)d_in[21];
  const float* b2   = (const float*)d_in[22];
  float* out = (float*)d_out;

  // Workspace: 3 f16 half-slots (151 MB total). q/k live in d_out (exact fit),
  // both dead before the final kernel overwrites every element of d_out.
  const size_t HE = 25165824;           // elements per half-slot (tokens*192)
  f16* xp   = (f16*)d_ws;               // conv(x) -> res (in-place in ln_qkv)
  f16* vp   = xp + HE;                  // conv(v) -> fb (attn out) -> m (LN3, in-place)
  f16* vvb  = vp + HE;                  // reordered conv weights (early) -> v projection
  f16* qb   = (f16*)d_out;              // q (scratch in d_out)
  f16* kb   = qb + HE;                  // k (scratch in d_out)
  f16* fb   = vp;                       // alias: vp dead after ln_qkv
  f16* Wr   = vvb;                      // 2*192*864 f16 = 663 KB, dead before ln_qkv writes vvb

  reorder_w<<<1296, 256, 0, stream>>>(pq_w, pv_w, Wr);
  conv3x3_mfma<<<4096, 256, 0, stream>>>(x, v, Wr, pq_b, pv_b, xp, vp);
  ln_qkv_mfma<<<4096, 256, 0, stream>>>(xp, vp, n1w, n1b, n2w, n2b, qW, kvW, qb, kb, vvb);
  attn64<<<16384, 64, 0, stream>>>(qb, kb, vvb, rpb, fb);
  ap_ln3_mfma<<<2048, 256, 0, stream>>>(fb, apW, apb, n3w, n3b);
  mlp_mfma<<<4096, 256, 0, stream>>>(fb, w1, b1, w2, b2, n4w, n4b, fb == vp ? xp : xp, out);
}